// Round 2
// baseline (714.944 us; speedup 1.0000x reference)
//
#include <hip/hip_runtime.h>
#include <hip/hip_bf16.h>
#include <math.h>

#define DIN 256
#define EDIM 16
#define HC 128          // H*C
#define BM 16           // nodes per block in GEMM

// ---------------- prep: W_c = W_ep @ W_e, b_c = b_ep @ W_e, zero deg ----------
__global__ void k_prep(const float* __restrict__ W_ep, const float* __restrict__ b_ep,
                       const float* __restrict__ W_e,
                       float* __restrict__ Wc, float* __restrict__ bc,
                       int* __restrict__ deg, int n) {
    int tid = blockIdx.x * blockDim.x + threadIdx.x;
    if (tid < n) deg[tid] = 0;
    if (tid < EDIM * HC) {
        int k = tid >> 7, j = tid & 127;
        float s = 0.f;
        for (int d = 0; d < DIN; ++d) s += W_ep[k * DIN + d] * W_e[d * HC + j];
        Wc[tid] = s;
    } else if (tid < EDIM * HC + HC) {
        int j = tid - EDIM * HC;
        float s = 0.f;
        for (int d = 0; d < DIN; ++d) s += b_ep[d] * W_e[d * HC + j];
        bc[j] = s;
    }
}

// ---------------- GEMM: xl = x@W_l + b_l ; xr = x@W_r + b_r -------------------
// 256 threads: t<128 -> xl column t; t>=128 -> xr column t-128. BM nodes/block.
__global__ __launch_bounds__(256) void k_gemm(const float* __restrict__ x,
    const float* __restrict__ Wl, const float* __restrict__ bl,
    const float* __restrict__ Wr, const float* __restrict__ br,
    float* __restrict__ xl, float* __restrict__ xr, int n) {
    int n0 = blockIdx.x * BM;
    int t = threadIdx.x;
    const float* __restrict__ W = (t < 128) ? Wl : Wr;
    float* __restrict__ out     = (t < 128) ? xl : xr;
    int col = t & 127;
    float bias = (t < 128) ? bl[col] : br[col];

    float acc[BM];
#pragma unroll
    for (int m = 0; m < BM; ++m) acc[m] = 0.f;

    for (int k = 0; k < DIN; ++k) {
        float w = W[k * HC + col];
#pragma unroll
        for (int m = 0; m < BM; ++m) {
            int nm = n0 + m; if (nm >= n) nm = n - 1;   // uniform clamp
            acc[m] += x[(size_t)nm * DIN + k] * w;
        }
    }
#pragma unroll
    for (int m = 0; m < BM; ++m) {
        int nm = n0 + m;
        if (nm < n) out[(size_t)nm * HC + col] = acc[m] + bias;
    }
}

// ---------------- CSR build over dst --------------------------------------
__global__ void k_deg(const int* __restrict__ ei, int* __restrict__ deg, int E) {
    int e = blockIdx.x * blockDim.x + threadIdx.x;
    if (e < E) atomicAdd(&deg[ei[E + e]], 1);
}

__global__ __launch_bounds__(1024) void k_scan(const int* __restrict__ deg,
                                               int* __restrict__ off,
                                               int* __restrict__ cursor, int n) {
    __shared__ int sdata[1024];
    int t = threadIdx.x;
    int chunk = (n + 1023) / 1024;
    int b = t * chunk, e = min(b + chunk, n);
    int s = 0;
    for (int i = b; i < e; ++i) s += deg[i];
    sdata[t] = s;
    __syncthreads();
    for (int d = 1; d < 1024; d <<= 1) {
        int v = (t >= d) ? sdata[t - d] : 0;
        __syncthreads();
        sdata[t] += v;
        __syncthreads();
    }
    int run = (t == 0) ? 0 : sdata[t - 1];
    for (int i = b; i < e; ++i) {
        off[i] = run; cursor[i] = run; run += deg[i];
    }
    if (t == 1023) off[n] = sdata[1023];
}

__global__ void k_scatter(const int* __restrict__ ei, int* __restrict__ cursor,
                          int* __restrict__ eid, int* __restrict__ srcs, int E) {
    int e = blockIdx.x * blockDim.x + threadIdx.x;
    if (e < E) {
        int dst = ei[E + e];
        int p = atomicAdd(&cursor[dst], 1);
        eid[p] = e;
        srcs[p] = ei[e];
    }
}

// ---------------- fused per-node attention + aggregation ----------------------
// 128 threads = 2 waves; wave h handles head h, lane c = channel.
__global__ __launch_bounds__(128) void k_node(const float* __restrict__ xl,
    const float* __restrict__ xr, const float* __restrict__ Wc,
    const float* __restrict__ bc, const float* __restrict__ att,
    const float* __restrict__ bias, const int* __restrict__ off,
    const int* __restrict__ srcs, const int* __restrict__ eid,
    const float* __restrict__ edge_attr, float* __restrict__ out, int n) {
    int node = blockIdx.x;
    int t = threadIdx.x;

    float wc[EDIM];
#pragma unroll
    for (int k = 0; k < EDIM; ++k) wc[k] = Wc[k * HC + t];
    float bct   = bc[t];
    float att_t = att[t];
    float bia_t = bias[t];
    float xr_v  = xr[(size_t)node * HC + t];

    int p0 = off[node], p1 = off[node + 1];

    float M = -INFINITY, D = 0.f, acc = 0.f;
    for (int p = p0; p < p1; ++p) {
        int src = srcs[p];
        int e   = eid[p];
        float xl_v = xl[(size_t)src * HC + t];
        const float* __restrict__ ea = edge_attr + (size_t)e * EDIM;
        float ee = bct;
#pragma unroll
        for (int k = 0; k < EDIM; ++k) ee += ea[k] * wc[k];
        float m  = xl_v + xr_v + ee;
        float lr = m > 0.f ? m : 0.2f * m;
        float pc = lr * att_t;
#pragma unroll
        for (int d = 1; d < 64; d <<= 1) pc += __shfl_xor(pc, d, 64);
        float s = pc;   // same value on all 64 lanes of this wave (head)
        if (s > M) {
            float r = __expf(M - s);
            D *= r; acc *= r; M = s;
        }
        float w = __expf(s - M);
        D += w;
        acc += w * xl_v;
    }
    float res = (D > 0.f) ? acc / D : 0.f;
    out[(size_t)node * HC + t] = res + bia_t;
}

// -----------------------------------------------------------------------------
extern "C" void kernel_launch(void* const* d_in, const int* in_sizes, int n_in,
                              void* d_out, int out_size, void* d_ws, size_t ws_size,
                              hipStream_t stream) {
    const float* x    = (const float*)d_in[0];
    const int*   ei   = (const int*)d_in[1];
    const float* eatt = (const float*)d_in[2];
    const float* W_ep = (const float*)d_in[3];
    const float* b_ep = (const float*)d_in[4];
    const float* W_l  = (const float*)d_in[5];
    const float* b_l  = (const float*)d_in[6];
    const float* W_r  = (const float*)d_in[7];
    const float* b_r  = (const float*)d_in[8];
    const float* W_e  = (const float*)d_in[9];
    const float* att  = (const float*)d_in[10];
    const float* bias = (const float*)d_in[11];
    float* out = (float*)d_out;

    const int N = in_sizes[0] / DIN;
    const int E = in_sizes[1] / 2;

    // workspace layout
    char* w = (char*)d_ws;
    size_t o = 0;
    auto alloc = [&](size_t bytes) {
        o = (o + 255) & ~(size_t)255;
        void* p = w + o;
        o += bytes;
        return p;
    };
    float* xl     = (float*)alloc((size_t)N * HC * sizeof(float));
    float* xr     = (float*)alloc((size_t)N * HC * sizeof(float));
    float* Wc     = (float*)alloc(EDIM * HC * sizeof(float));
    float* bc     = (float*)alloc(HC * sizeof(float));
    int*   deg    = (int*)alloc((size_t)N * sizeof(int));
    int*   off    = (int*)alloc(((size_t)N + 1) * sizeof(int));
    int*   cursor = (int*)alloc((size_t)N * sizeof(int));
    int*   eid    = (int*)alloc((size_t)E * sizeof(int));
    int*   srcs   = (int*)alloc((size_t)E * sizeof(int));

    int prep_threads = (N > EDIM * HC + HC) ? N : (EDIM * HC + HC);
    k_prep<<<(prep_threads + 255) / 256, 256, 0, stream>>>(W_ep, b_ep, W_e, Wc, bc, deg, N);

    k_gemm<<<(N + BM - 1) / BM, 256, 0, stream>>>(x, W_l, b_l, W_r, b_r, xl, xr, N);

    k_deg<<<(E + 255) / 256, 256, 0, stream>>>(ei, deg, E);
    k_scan<<<1, 1024, 0, stream>>>(deg, off, cursor, N);
    k_scatter<<<(E + 255) / 256, 256, 0, stream>>>(ei, cursor, eid, srcs, E);

    k_node<<<N, 128, 0, stream>>>(xl, xr, Wc, bc, att, bias, off, srcs, eid,
                                  eatt, out, N);
}

// Round 3
// 399.494 us; speedup vs baseline: 1.7896x; 1.7896x over previous
//
#include <hip/hip_runtime.h>
#include <hip/hip_bf16.h>
#include <math.h>

#define DIN 256
#define EDIM 16
#define HC 128          // H*C
#define GBM 128         // GEMM tile M
#define GBN 256         // GEMM tile N (Wl cols | Wr cols)
#define GBK 32          // GEMM K step
#define LDS_STRIDE 40   // padded LDS row stride in shorts (40*2B=80B, 16B-aligned, conflict-light)

typedef __attribute__((ext_vector_type(8))) short short8v;       // bf16 x8 (4 VGPR)
typedef __attribute__((ext_vector_type(4))) float floatx4;
typedef __attribute__((ext_vector_type(4))) unsigned short ushort4v;

__device__ inline unsigned short f2bf(float f) {
    union { float f; unsigned u; } v; v.f = f;
    unsigned r = v.u + 0x7FFF + ((v.u >> 16) & 1);   // RNE
    return (unsigned short)(r >> 16);
}

// ---------------- prep: W_c = W_ep @ W_e, b_c = b_ep @ W_e --------------------
__global__ void k_prep(const float* __restrict__ W_ep, const float* __restrict__ b_ep,
                       const float* __restrict__ W_e,
                       float* __restrict__ Wc, float* __restrict__ bc) {
    int tid = blockIdx.x * blockDim.x + threadIdx.x;
    if (tid < EDIM * HC) {
        int k = tid >> 7, j = tid & 127;
        float s = 0.f;
        for (int d = 0; d < DIN; ++d) s += W_ep[k * DIN + d] * W_e[d * HC + j];
        Wc[tid] = s;
    } else if (tid < EDIM * HC + HC) {
        int j = tid - EDIM * HC;
        float s = 0.f;
        for (int d = 0; d < DIN; ++d) s += b_ep[d] * W_e[d * HC + j];
        bc[j] = s;
    }
}

// ---------------- Wb[col][k] = bf16(Wl|Wr transposed) -------------------------
__global__ void k_convw(const float* __restrict__ Wl, const float* __restrict__ Wr,
                        unsigned short* __restrict__ Wb) {
    int col = blockIdx.x, k = threadIdx.x;
    float v = (col < HC) ? Wl[(size_t)k * HC + col] : Wr[(size_t)k * HC + (col - HC)];
    Wb[(size_t)col * DIN + k] = f2bf(v);
}

// ---------------- MFMA GEMM: [xl | xr] = x @ [Wl | Wr] + [bl | br] ------------
// 256 threads = 4 waves (2x2 wave grid). Each wave: 64 rows x 128 cols.
__global__ __launch_bounds__(256) void k_mm(const float* __restrict__ x,
    const unsigned short* __restrict__ Wb,
    const float* __restrict__ bl, const float* __restrict__ br,
    float* __restrict__ xl, float* __restrict__ xr, int M) {
    __shared__ unsigned short As[GBM * LDS_STRIDE];   // 10240 B
    __shared__ unsigned short Bs[GBN * LDS_STRIDE];   // 20480 B

    int t = threadIdx.x;
    int wid = t >> 6, lane = t & 63;
    int wm = wid >> 1, wn = wid & 1;
    int m0 = blockIdx.x * GBM;

    floatx4 acc[4][8];
#pragma unroll
    for (int i = 0; i < 4; ++i)
#pragma unroll
        for (int j = 0; j < 8; ++j) acc[i][j] = (floatx4){0.f, 0.f, 0.f, 0.f};

    int row_l = lane & 15, kg = (lane >> 4) * 8;

    for (int kb = 0; kb < DIN; kb += GBK) {
        // stage A: 128 rows x 32 floats -> bf16. 1024 float4 chunks, 4/thread.
#pragma unroll
        for (int j = 0; j < 4; ++j) {
            int c = t + 256 * j;
            int r = c >> 3, kk = (c & 7) * 4;
            int gr = m0 + r; if (gr >= M) gr = M - 1;
            floatx4 v = *(const floatx4*)(x + (size_t)gr * DIN + kb + kk);
            ushort4v u;
            u[0] = f2bf(v[0]); u[1] = f2bf(v[1]); u[2] = f2bf(v[2]); u[3] = f2bf(v[3]);
            *(ushort4v*)(&As[r * LDS_STRIDE + kk]) = u;
        }
        // stage B: 256 cols x 32 bf16. 1024 short8 chunks? -> 8192 shorts = 1024 x 8; 4/thread.
#pragma unroll
        for (int j = 0; j < 4; ++j) {
            int c = t + 256 * j;
            int col = c >> 2, kk = (c & 3) * 8;
            short8v v = *(const short8v*)(Wb + (size_t)col * DIN + kb + kk);
            *(short8v*)(&Bs[col * LDS_STRIDE + kk]) = v;
        }
        __syncthreads();

        short8v a[4], b[8];
#pragma unroll
        for (int i = 0; i < 4; ++i)
            a[i] = *(short8v*)(&As[(wm * 64 + i * 16 + row_l) * LDS_STRIDE + kg]);
#pragma unroll
        for (int j = 0; j < 8; ++j)
            b[j] = *(short8v*)(&Bs[(wn * 128 + j * 16 + row_l) * LDS_STRIDE + kg]);
#pragma unroll
        for (int i = 0; i < 4; ++i)
#pragma unroll
            for (int j = 0; j < 8; ++j)
                acc[i][j] = __builtin_amdgcn_mfma_f32_16x16x32_bf16(a[i], b[j], acc[i][j], 0, 0, 0);
        __syncthreads();
    }

    // epilogue: C/D layout col = lane&15, row = (lane>>4)*4 + q
    int colf = lane & 15, rq = (lane >> 4) * 4;
#pragma unroll
    for (int j = 0; j < 8; ++j) {
        int col = wn * 128 + j * 16 + colf;
        float* outp; int oc; float bs;
        if (col < HC) { outp = xl; oc = col; bs = bl[col]; }
        else          { outp = xr; oc = col - HC; bs = br[col - HC]; }
#pragma unroll
        for (int i = 0; i < 4; ++i) {
#pragma unroll
            for (int q = 0; q < 4; ++q) {
                int row = m0 + wm * 64 + i * 16 + rq + q;
                if (row < M) outp[(size_t)row * HC + oc] = acc[i][j][q] + bs;
            }
        }
    }
}

// ---------------- CSR build over dst ------------------------------------------
__global__ void k_deg(const int* __restrict__ ei, int* __restrict__ deg, int E) {
    int e = blockIdx.x * blockDim.x + threadIdx.x;
    if (e < E) atomicAdd(&deg[ei[E + e]], 1);
}

__global__ __launch_bounds__(1024) void k_scan(const int* __restrict__ deg,
                                               int* __restrict__ off,
                                               int* __restrict__ cursor, int n) {
    __shared__ int sdata[1024];
    int t = threadIdx.x;
    int chunk = (n + 1023) / 1024;
    int b = t * chunk, e = min(b + chunk, n);
    int s = 0;
    for (int i = b; i < e; ++i) s += deg[i];
    sdata[t] = s;
    __syncthreads();
    for (int d = 1; d < 1024; d <<= 1) {
        int v = (t >= d) ? sdata[t - d] : 0;
        __syncthreads();
        sdata[t] += v;
        __syncthreads();
    }
    int run = (t == 0) ? 0 : sdata[t - 1];
    for (int i = b; i < e; ++i) {
        off[i] = run; cursor[i] = run; run += deg[i];
    }
    if (t == 1023) off[n] = sdata[1023];
}

__global__ void k_scatter(const int* __restrict__ ei, int* __restrict__ cursor,
                          int* __restrict__ eid, int* __restrict__ srcs, int E) {
    int e = blockIdx.x * blockDim.x + threadIdx.x;
    if (e < E) {
        int dst = ei[E + e];
        int p = atomicAdd(&cursor[dst], 1);
        eid[p] = e;
        srcs[p] = ei[e];
    }
}

// ---------------- fused per-node attention + aggregation ----------------------
// 128 threads = 2 waves; wave h = head h, lane = channel. Unroll-2 over edges.
__global__ __launch_bounds__(128) void k_node(const float* __restrict__ xl,
    const float* __restrict__ xr, const float* __restrict__ Wc,
    const float* __restrict__ bc, const float* __restrict__ att,
    const float* __restrict__ bias, const int* __restrict__ off,
    const int* __restrict__ srcs, const int* __restrict__ eid,
    const float* __restrict__ edge_attr, float* __restrict__ out, int n) {
    int node = blockIdx.x;
    int t = threadIdx.x;

    float wc[EDIM];
#pragma unroll
    for (int k = 0; k < EDIM; ++k) wc[k] = Wc[k * HC + t];
    float bct   = bc[t];
    float att_t = att[t];
    float bia_t = bias[t];
    float xr_v  = xr[(size_t)node * HC + t];

    int p0 = off[node], p1 = off[node + 1];

    float M = -INFINITY, D = 0.f, acc = 0.f;
    int p = p0;
    for (; p + 1 < p1; p += 2) {
        int s0 = srcs[p], s1 = srcs[p + 1];
        int e0 = eid[p],  e1 = eid[p + 1];
        float xl0 = xl[(size_t)s0 * HC + t];
        float xl1 = xl[(size_t)s1 * HC + t];
        const float* __restrict__ ea0 = edge_attr + (size_t)e0 * EDIM;
        const float* __restrict__ ea1 = edge_attr + (size_t)e1 * EDIM;
        float ee0 = bct, ee1 = bct;
#pragma unroll
        for (int k = 0; k < EDIM; ++k) { ee0 += ea0[k] * wc[k]; ee1 += ea1[k] * wc[k]; }
        float m0 = xl0 + xr_v + ee0;
        float m1 = xl1 + xr_v + ee1;
        float l0 = m0 > 0.f ? m0 : 0.2f * m0;
        float l1 = m1 > 0.f ? m1 : 0.2f * m1;
        float pc0 = l0 * att_t, pc1 = l1 * att_t;
#pragma unroll
        for (int d = 1; d < 64; d <<= 1) {
            pc0 += __shfl_xor(pc0, d, 64);
            pc1 += __shfl_xor(pc1, d, 64);
        }
        float mn = fmaxf(M, fmaxf(pc0, pc1));
        float cr = __expf(M - mn);
        float w0 = __expf(pc0 - mn), w1 = __expf(pc1 - mn);
        D   = D * cr + w0 + w1;
        acc = acc * cr + w0 * xl0 + w1 * xl1;
        M = mn;
    }
    if (p < p1) {
        int s0 = srcs[p], e0 = eid[p];
        float xl0 = xl[(size_t)s0 * HC + t];
        const float* __restrict__ ea0 = edge_attr + (size_t)e0 * EDIM;
        float ee0 = bct;
#pragma unroll
        for (int k = 0; k < EDIM; ++k) ee0 += ea0[k] * wc[k];
        float m0 = xl0 + xr_v + ee0;
        float l0 = m0 > 0.f ? m0 : 0.2f * m0;
        float pc0 = l0 * att_t;
#pragma unroll
        for (int d = 1; d < 64; d <<= 1) pc0 += __shfl_xor(pc0, d, 64);
        float mn = fmaxf(M, pc0);
        float cr = __expf(M - mn);
        float w0 = __expf(pc0 - mn);
        D   = D * cr + w0;
        acc = acc * cr + w0 * xl0;
        M = mn;
    }
    float res = (D > 0.f) ? acc / D : 0.f;
    out[(size_t)node * HC + t] = res + bia_t;
}

// -----------------------------------------------------------------------------
extern "C" void kernel_launch(void* const* d_in, const int* in_sizes, int n_in,
                              void* d_out, int out_size, void* d_ws, size_t ws_size,
                              hipStream_t stream) {
    const float* x    = (const float*)d_in[0];
    const int*   ei   = (const int*)d_in[1];
    const float* eatt = (const float*)d_in[2];
    const float* W_ep = (const float*)d_in[3];
    const float* b_ep = (const float*)d_in[4];
    const float* W_l  = (const float*)d_in[5];
    const float* b_l  = (const float*)d_in[6];
    const float* W_r  = (const float*)d_in[7];
    const float* b_r  = (const float*)d_in[8];
    const float* W_e  = (const float*)d_in[9];
    const float* att  = (const float*)d_in[10];
    const float* bias = (const float*)d_in[11];
    float* out = (float*)d_out;

    const int N = in_sizes[0] / DIN;
    const int E = in_sizes[1] / 2;

    char* w = (char*)d_ws;
    size_t o = 0;
    auto alloc = [&](size_t bytes) {
        o = (o + 255) & ~(size_t)255;
        void* p = w + o;
        o += bytes;
        return p;
    };
    float* xl              = (float*)alloc((size_t)N * HC * sizeof(float));
    float* xr              = (float*)alloc((size_t)N * HC * sizeof(float));
    unsigned short* Wb     = (unsigned short*)alloc((size_t)GBN * DIN * sizeof(unsigned short));
    float* Wc              = (float*)alloc(EDIM * HC * sizeof(float));
    float* bc              = (float*)alloc(HC * sizeof(float));
    int*   deg             = (int*)alloc((size_t)N * sizeof(int));
    int*   off             = (int*)alloc(((size_t)N + 1) * sizeof(int));
    int*   cursor          = (int*)alloc((size_t)N * sizeof(int));
    int*   eid             = (int*)alloc((size_t)E * sizeof(int));
    int*   srcs            = (int*)alloc((size_t)E * sizeof(int));

    hipMemsetAsync(deg, 0, (size_t)N * sizeof(int), stream);

    k_prep<<<(EDIM * HC + HC + 255) / 256, 256, 0, stream>>>(W_ep, b_ep, W_e, Wc, bc);
    k_convw<<<GBN, DIN, 0, stream>>>(W_l, W_r, Wb);

    k_mm<<<(N + GBM - 1) / GBM, 256, 0, stream>>>(x, Wb, b_l, b_r, xl, xr, N);

    k_deg<<<(E + 255) / 256, 256, 0, stream>>>(ei, deg, E);
    k_scan<<<1, 1024, 0, stream>>>(deg, off, cursor, N);
    k_scatter<<<(E + 255) / 256, 256, 0, stream>>>(ei, cursor, eid, srcs, E);

    k_node<<<N, 128, 0, stream>>>(xl, xr, Wc, bc, att, bias, off, srcs, eid,
                                  eatt, out, N);
}